// Round 2
// baseline (3311.077 us; speedup 1.0000x reference)
//
#include <hip/hip_runtime.h>
#include <math.h>

#define NNODES 200000
#define NG 1000
#define NPG 200
#define KNN 5
#define MD 128
#define S6 (1.0f / 6.0f)

// ---------------- kNN: one block per graph (validated in R1) ----------------
__global__ __launch_bounds__(256) void knn_kernel(const float* __restrict__ pos,
                                                  int* __restrict__ knn) {
  __shared__ float sp[NPG * 3];
  int g = blockIdx.x;
  int t = threadIdx.x;
  for (int i = t; i < NPG * 3; i += 256) sp[i] = pos[(size_t)g * NPG * 3 + i];
  __syncthreads();
  if (t < NPG) {
    float x = sp[t * 3 + 0], y = sp[t * 3 + 1], z = sp[t * 3 + 2];
    float bd[KNN];
    int bi[KNN];
#pragma unroll
    for (int k = 0; k < KNN; k++) { bd[k] = 3.0e38f; bi[k] = 0; }
    for (int j = 0; j < NPG; j++) {
      if (j == t) continue;
      float dx = __fsub_rn(x, sp[j * 3 + 0]);
      float dy = __fsub_rn(y, sp[j * 3 + 1]);
      float dz = __fsub_rn(z, sp[j * 3 + 2]);
      float d2 = __fadd_rn(__fadd_rn(__fmul_rn(dx, dx), __fmul_rn(dy, dy)),
                           __fmul_rn(dz, dz));
      if (d2 < bd[KNN - 1]) {
        bd[KNN - 1] = d2; bi[KNN - 1] = j;
#pragma unroll
        for (int k = KNN - 1; k > 0; k--) {
          if (bd[k] < bd[k - 1]) {
            float td = bd[k]; bd[k] = bd[k - 1]; bd[k - 1] = td;
            int ti = bi[k]; bi[k] = bi[k - 1]; bi[k - 1] = ti;
          }
        }
      }
    }
#pragma unroll
    for (int k = 0; k < KNN; k++)
      knn[((size_t)g * NPG + t) * KNN + k] = g * NPG + bi[k];
  }
}

// ---------------- embW0 = emb @ W0 (100x128 @ 128x128) ----------------
__global__ __launch_bounds__(256) void emb_gemm_kernel(const float* __restrict__ emb,
                                                       const float* __restrict__ W,
                                                       float* __restrict__ embW) {
  int idx = blockIdx.x * 256 + threadIdx.x;  // 12800 total
  int r = idx >> 7, c = idx & 127;
  float a = 0.0f;
  for (int k = 0; k < MD; k++) a += emb[r * MD + k] * W[k * MD + c];
  embW[idx] = a;
}

// 32 FMAs for one (row i) at k-quad q: acc[2 col-halves of float4]
#define FMA_BLOCK(ACC0, ACC1, A4, B0, B1)                                    \
  do {                                                                       \
    ACC0.x += A4.x * B0[0].x + A4.y * B0[1].x + A4.z * B0[2].x + A4.w * B0[3].x; \
    ACC0.y += A4.x * B0[0].y + A4.y * B0[1].y + A4.z * B0[2].y + A4.w * B0[3].y; \
    ACC0.z += A4.x * B0[0].z + A4.y * B0[1].z + A4.z * B0[2].z + A4.w * B0[3].z; \
    ACC0.w += A4.x * B0[0].w + A4.y * B0[1].w + A4.z * B0[2].w + A4.w * B0[3].w; \
    ACC1.x += A4.x * B1[0].x + A4.y * B1[1].x + A4.z * B1[2].x + A4.w * B1[3].x; \
    ACC1.y += A4.x * B1[0].y + A4.y * B1[1].y + A4.z * B1[2].y + A4.w * B1[3].y; \
    ACC1.z += A4.x * B1[0].z + A4.y * B1[1].z + A4.z * B1[2].z + A4.w * B1[3].z; \
    ACC1.w += A4.x * B1[0].w + A4.y * B1[1].w + A4.z * B1[2].w + A4.w * B1[3].w; \
  } while (0)

// ---------------- fused GEMM template body ----------------
// BM=256, BN=128, BK=32. Thread tile: 16 rows (stride 16) x 8 cols ({4c,64+4c}).
// As[256][36] row-major (pad 36 => conflict-free b128 reads at row-stride 16),
// Bs[32][128]. MODE 0: A-rows built from embW gathers (layer1 fused).
// MODE 1: A-rows built from h-gather aggregation (agg fused).

template <int MODE>
__device__ __forceinline__ void gemm_fused_body(
    const int* __restrict__ z, const int* __restrict__ knn,
    const float* __restrict__ gsrc,  // MODE 0: embW[100][128]; MODE 1: h[N][128]
    const float* __restrict__ bias,  // layer bias applied pre-relu [128]
    const float* __restrict__ W,     // [128][128] k-major
    float* __restrict__ C) {
  __shared__ float As[256 * 36];
  __shared__ float Bs[32 * 128];
  const int tid = threadIdx.x;
  const int row0 = blockIdx.x * 256;
  const int colg = tid & 15;
  const int rowg = tid >> 4;

  float4 acc[16][2];
#pragma unroll
  for (int i = 0; i < 16; i++) {
    acc[i][0] = make_float4(0.f, 0.f, 0.f, 0.f);
    acc[i][1] = make_float4(0.f, 0.f, 0.f, 0.f);
  }

  const float4* G4 = (const float4*)gsrc;

  for (int k0 = 0; k0 < MD; k0 += 32) {
    // ---- stage B: 32x128, 4 float4 per thread, straight copy ----
#pragma unroll
    for (int i = 0; i < 4; i++) {
      int id = tid + 256 * i;
      int k = id >> 5, c4 = id & 31;
      float4 w = *(const float4*)(W + (size_t)(k0 + k) * MD + c4 * 4);
      *(float4*)(Bs + k * MD + c4 * 4) = w;
    }
    // ---- stage A: build activation tile on the fly, 8 float4 slots/thread ----
#pragma unroll
    for (int i = 0; i < 8; i++) {
      int id = tid + 256 * i;
      int r = id >> 3, kq = id & 7;
      int row = row0 + r;
      if (row >= NNODES) row = NNODES - 1;
      const int* kn = knn + (size_t)row * KNN;
      int koff = (k0 >> 2) + kq;  // float4 index within 128-wide row
      float4 s;
      if (MODE == 0) {
        int z0 = z[row];
        int z1 = z[kn[0]], z2 = z[kn[1]], z3 = z[kn[2]], z4 = z[kn[3]], z5 = z[kn[4]];
        s = G4[(size_t)z0 * 32 + koff];
        float4 t1 = G4[(size_t)z1 * 32 + koff]; s.x += t1.x; s.y += t1.y; s.z += t1.z; s.w += t1.w;
        float4 t2 = G4[(size_t)z2 * 32 + koff]; s.x += t2.x; s.y += t2.y; s.z += t2.z; s.w += t2.w;
        float4 t3 = G4[(size_t)z3 * 32 + koff]; s.x += t3.x; s.y += t3.y; s.z += t3.z; s.w += t3.w;
        float4 t4 = G4[(size_t)z4 * 32 + koff]; s.x += t4.x; s.y += t4.y; s.z += t4.z; s.w += t4.w;
        float4 t5 = G4[(size_t)z5 * 32 + koff]; s.x += t5.x; s.y += t5.y; s.z += t5.z; s.w += t5.w;
      } else {
        s = G4[(size_t)row * 32 + koff];
        int n0 = kn[0], n1 = kn[1], n2 = kn[2], n3 = kn[3], n4 = kn[4];
        float4 t1 = G4[(size_t)n0 * 32 + koff]; s.x += t1.x; s.y += t1.y; s.z += t1.z; s.w += t1.w;
        float4 t2 = G4[(size_t)n1 * 32 + koff]; s.x += t2.x; s.y += t2.y; s.z += t2.z; s.w += t2.w;
        float4 t3 = G4[(size_t)n2 * 32 + koff]; s.x += t3.x; s.y += t3.y; s.z += t3.z; s.w += t3.w;
        float4 t4 = G4[(size_t)n3 * 32 + koff]; s.x += t4.x; s.y += t4.y; s.z += t4.z; s.w += t4.w;
        float4 t5 = G4[(size_t)n4 * 32 + koff]; s.x += t5.x; s.y += t5.y; s.z += t5.z; s.w += t5.w;
      }
      float4 bb = *(const float4*)(bias + k0 + kq * 4);
      float4 v;
      v.x = fmaxf(s.x * S6 + bb.x, 0.0f);
      v.y = fmaxf(s.y * S6 + bb.y, 0.0f);
      v.z = fmaxf(s.z * S6 + bb.z, 0.0f);
      v.w = fmaxf(s.w * S6 + bb.w, 0.0f);
      *(float4*)(As + r * 36 + kq * 4) = v;
    }
    __syncthreads();
    // ---- inner: 8 k-quads, per thread 16 rows x 8 cols ----
#pragma unroll
    for (int q = 0; q < 8; q++) {
      float4 b0[4], b1[4];
#pragma unroll
      for (int kk = 0; kk < 4; kk++) {
        const float* Br = Bs + (4 * q + kk) * MD;
        b0[kk] = *(const float4*)(Br + colg * 4);
        b1[kk] = *(const float4*)(Br + 64 + colg * 4);
      }
#pragma unroll
      for (int i = 0; i < 16; i++) {
        float4 a = *(const float4*)(As + (rowg + 16 * i) * 36 + q * 4);
        FMA_BLOCK(acc[i][0], acc[i][1], a, b0, b1);
      }
    }
    __syncthreads();
  }
  // ---- store ----
#pragma unroll
  for (int i = 0; i < 16; i++) {
    int row = row0 + rowg + 16 * i;
    if (row < NNODES) {
      *(float4*)(C + (size_t)row * MD + colg * 4) = acc[i][0];
      *(float4*)(C + (size_t)row * MD + 64 + colg * 4) = acc[i][1];
    }
  }
}

__global__ __launch_bounds__(256, 2) void gemm_l1_kernel(
    const int* __restrict__ z, const int* __restrict__ knn,
    const float* __restrict__ embW, const float* __restrict__ b0,
    const float* __restrict__ W, float* __restrict__ C) {
  gemm_fused_body<0>(z, knn, embW, b0, W, C);
}

__global__ __launch_bounds__(256, 2) void gemm_l2_kernel(
    const int* __restrict__ knn, const float* __restrict__ h,
    const float* __restrict__ b1, const float* __restrict__ W,
    float* __restrict__ C) {
  gemm_fused_body<1>(nullptr, knn, h, b1, W, C);
}

// ---------------- tail: agg(layer3) + mean-pool + MLP, one block per graph ----------------
__global__ __launch_bounds__(256) void tail_kernel(
    const float* __restrict__ h3, const int* __restrict__ knn,
    const float* __restrict__ b2, const float* __restrict__ rW1,
    const float* __restrict__ rb1, const float* __restrict__ rW2,
    const float* __restrict__ rb2, const float* __restrict__ rW3,
    const float* __restrict__ rb3, float* __restrict__ out) {
  __shared__ int kl[NPG * KNN];       // global neighbor ids for this graph
  __shared__ float part[8 * MD];      // per-group pooled partials
  __shared__ float pooled[MD];
  __shared__ float h1s[64];
  __shared__ float h2s[32];
  int g = blockIdx.x;
  int t = threadIdx.x;
  // stage knn (1000 ints = 250 int4)
  if (t < 250) ((int4*)kl)[t] = ((const int4*)(knn + (size_t)g * NPG * KNN))[t];
  __syncthreads();

  const float4* H = (const float4*)h3;  // global-id indexed
  int group = t >> 5;       // 0..7 -> 25 nodes each
  int cq = t & 31;          // float4 column index
  float4 bb = ((const float4*)b2)[cq];
  float4 pool = make_float4(0.f, 0.f, 0.f, 0.f);
  for (int j = 0; j < 25; j++) {
    int n = group * 25 + j;               // local node
    size_t gn = (size_t)g * NPG + n;      // global node
    const int* kn = kl + n * KNN;
    float4 s = H[gn * 32 + cq];
    int n0 = kn[0], n1 = kn[1], n2 = kn[2], n3 = kn[3], n4 = kn[4];
    float4 t1 = H[(size_t)n0 * 32 + cq]; s.x += t1.x; s.y += t1.y; s.z += t1.z; s.w += t1.w;
    float4 t2 = H[(size_t)n1 * 32 + cq]; s.x += t2.x; s.y += t2.y; s.z += t2.z; s.w += t2.w;
    float4 t3 = H[(size_t)n2 * 32 + cq]; s.x += t3.x; s.y += t3.y; s.z += t3.z; s.w += t3.w;
    float4 t4 = H[(size_t)n3 * 32 + cq]; s.x += t4.x; s.y += t4.y; s.z += t4.z; s.w += t4.w;
    float4 t5 = H[(size_t)n4 * 32 + cq]; s.x += t5.x; s.y += t5.y; s.z += t5.z; s.w += t5.w;
    pool.x += fmaxf(s.x * S6 + bb.x, 0.0f);
    pool.y += fmaxf(s.y * S6 + bb.y, 0.0f);
    pool.z += fmaxf(s.z * S6 + bb.z, 0.0f);
    pool.w += fmaxf(s.w * S6 + bb.w, 0.0f);
  }
  ((float4*)part)[group * 32 + cq] = pool;
  __syncthreads();
  if (t < 32) {
    float4 p = make_float4(0.f, 0.f, 0.f, 0.f);
    for (int gr = 0; gr < 8; gr++) {
      float4 q = ((const float4*)part)[gr * 32 + t];
      p.x += q.x; p.y += q.y; p.z += q.z; p.w += q.w;
    }
    const float inv = 1.0f / (float)NPG;
    p.x *= inv; p.y *= inv; p.z *= inv; p.w *= inv;
    ((float4*)pooled)[t] = p;
  }
  __syncthreads();
  if (t < 64) {
    float a = rb1[t];
    for (int c = 0; c < 128; c++) a += pooled[c] * rW1[c * 64 + t];
    h1s[t] = fmaxf(a, 0.0f);
  }
  __syncthreads();
  if (t < 32) {
    float a = rb2[t];
    for (int c = 0; c < 64; c++) a += h1s[c] * rW2[c * 32 + t];
    h2s[t] = fmaxf(a, 0.0f);
  }
  __syncthreads();
  if (t == 0) {
    float a = rb3[0];
    for (int c = 0; c < 32; c++) a += h2s[c] * rW3[c];
    out[g] = a;
  }
}

extern "C" void kernel_launch(void* const* d_in, const int* in_sizes, int n_in,
                              void* d_out, int out_size, void* d_ws, size_t ws_size,
                              hipStream_t stream) {
  const int* z = (const int*)d_in[0];
  const float* pos = (const float*)d_in[1];
  const float* emb = (const float*)d_in[3];
  const float* convW = (const float*)d_in[4];  // [3][128][128]
  const float* convb = (const float*)d_in[5];  // [3][128]
  const float* rW1 = (const float*)d_in[6];
  const float* rb1 = (const float*)d_in[7];
  const float* rW2 = (const float*)d_in[8];
  const float* rb2 = (const float*)d_in[9];
  const float* rW3 = (const float*)d_in[10];
  const float* rb3 = (const float*)d_in[11];
  float* out = (float*)d_out;

  char* ws = (char*)d_ws;
  int* knn = (int*)ws;                                     // 4,000,000 B
  float* hA = (float*)(ws + 4000000);                      // 102,400,000 B (h2)
  float* hB = (float*)(ws + 4000000 + 102400000ULL);       // 102,400,000 B (h3)
  float* embW = (float*)(ws + 4000000 + 2 * 102400000ULL); // 51,200 B

  knn_kernel<<<NG, 256, 0, stream>>>(pos, knn);
  emb_gemm_kernel<<<50, 256, 0, stream>>>(emb, convW, embW);

  const int gemm_grid = (NNODES + 255) / 256;  // 782
  // layer 1 fused into GEMM-A staging: h2 = relu-agg(embW[z]) @ W1
  gemm_l1_kernel<<<gemm_grid, 256, 0, stream>>>(z, knn, embW, convb,
                                                convW + (size_t)1 * MD * MD, hA);
  // layer 2 agg fused into GEMM-B staging: h3 = relu-agg(h2) @ W2
  gemm_l2_kernel<<<gemm_grid, 256, 0, stream>>>(knn, hA, convb + MD,
                                                convW + (size_t)2 * MD * MD, hB);
  // layer 3 agg + mean-pool + MLP
  tail_kernel<<<NG, 256, 0, stream>>>(hB, knn, convb + 2 * MD, rW1, rb1, rW2,
                                      rb2, rW3, rb3, out);
}

// Round 3
// 422.047 us; speedup vs baseline: 7.8453x; 7.8453x over previous
//
#include <hip/hip_runtime.h>
#include <math.h>

#define NNODES 200000
#define NG 1000
#define NPG 200
#define KNN 5
#define MD 128
#define S6 (1.0f / 6.0f)

// ---------------- kNN: one block per graph (validated R1) ----------------
__global__ __launch_bounds__(256) void knn_kernel(const float* __restrict__ pos,
                                                  int* __restrict__ knn) {
  __shared__ float sp[NPG * 3];
  int g = blockIdx.x;
  int t = threadIdx.x;
  for (int i = t; i < NPG * 3; i += 256) sp[i] = pos[(size_t)g * NPG * 3 + i];
  __syncthreads();
  if (t < NPG) {
    float x = sp[t * 3 + 0], y = sp[t * 3 + 1], z = sp[t * 3 + 2];
    float bd[KNN];
    int bi[KNN];
#pragma unroll
    for (int k = 0; k < KNN; k++) { bd[k] = 3.0e38f; bi[k] = 0; }
    for (int j = 0; j < NPG; j++) {
      if (j == t) continue;
      float dx = __fsub_rn(x, sp[j * 3 + 0]);
      float dy = __fsub_rn(y, sp[j * 3 + 1]);
      float dz = __fsub_rn(z, sp[j * 3 + 2]);
      float d2 = __fadd_rn(__fadd_rn(__fmul_rn(dx, dx), __fmul_rn(dy, dy)),
                           __fmul_rn(dz, dz));
      if (d2 < bd[KNN - 1]) {
        bd[KNN - 1] = d2; bi[KNN - 1] = j;
#pragma unroll
        for (int k = KNN - 1; k > 0; k--) {
          if (bd[k] < bd[k - 1]) {
            float td = bd[k]; bd[k] = bd[k - 1]; bd[k - 1] = td;
            int ti = bi[k]; bi[k] = bi[k - 1]; bi[k - 1] = ti;
          }
        }
      }
    }
#pragma unroll
    for (int k = 0; k < KNN; k++)
      knn[((size_t)g * NPG + t) * KNN + k] = g * NPG + bi[k];
  }
}

// ---------------- embW0 = emb @ W0 (100x128 @ 128x128) ----------------
__global__ __launch_bounds__(256) void emb_gemm_kernel(const float* __restrict__ emb,
                                                       const float* __restrict__ W,
                                                       float* __restrict__ embW) {
  int idx = blockIdx.x * 256 + threadIdx.x;  // 12800 total
  int r = idx >> 7, c = idx & 127;
  float a = 0.0f;
  for (int k = 0; k < MD; k++) a += emb[r * MD + k] * W[k * MD + c];
  embW[idx] = a;
}

// ---------------- fused agg + GEMM layer ----------------
// Block: 256 thr (4 waves). BM=64 rows, full 128 cols. Wave w -> cols 32w..32w+31,
// lane -> one row. A tile (post-agg, post-relu activation) staged ONCE in LDS,
// k-major As[128][64] (bank-conflict-free b32). B rows are wave-uniform ->
// scalar loads (SGPR), so LDS pipe sees only 1 ds_read_b32 per k per lane.
// acc = 32 VGPRs. MODE 0: A from embW[z[.]] (layer1). MODE 1: A from h rows.
template <int MODE>
__device__ __forceinline__ void layer_body(
    const int* __restrict__ z, const int* __restrict__ knn,
    const float* __restrict__ gsrc,  // MODE 0: embW[100][128]; MODE 1: h[N][128]
    const float* __restrict__ bias,  // this layer's bias (pre-relu) [128]
    const float* __restrict__ W,     // next weight [128][128] k-major
    float* __restrict__ C) {
  __shared__ float As[MD * 64];  // [k][row], 32 KB
  const int tid = threadIdx.x;
  const int row0 = blockIdx.x * 64;
  const int row = tid & 63;
  const int grow = row0 + row;

  // ---- stage A: fused gather-aggregate + bias + relu, k-major ----
  const int* kn = knn + (size_t)grow * KNN;
  int i0, i1, i2, i3, i4, i5;
  if (MODE == 0) {
    i0 = z[grow];
    i1 = z[kn[0]]; i2 = z[kn[1]]; i3 = z[kn[2]]; i4 = z[kn[3]]; i5 = z[kn[4]];
  } else {
    i0 = grow;
    i1 = kn[0]; i2 = kn[1]; i3 = kn[2]; i4 = kn[3]; i5 = kn[4];
  }
  const float4* G4 = (const float4*)gsrc;
  const float4* B4 = (const float4*)bias;
#pragma unroll
  for (int it = 0; it < 8; it++) {
    int kq = (tid >> 6) + 4 * it;  // float4 index in 128-wide row
    float4 s = G4[(size_t)i0 * 32 + kq];
    float4 t1 = G4[(size_t)i1 * 32 + kq]; s.x += t1.x; s.y += t1.y; s.z += t1.z; s.w += t1.w;
    float4 t2 = G4[(size_t)i2 * 32 + kq]; s.x += t2.x; s.y += t2.y; s.z += t2.z; s.w += t2.w;
    float4 t3 = G4[(size_t)i3 * 32 + kq]; s.x += t3.x; s.y += t3.y; s.z += t3.z; s.w += t3.w;
    float4 t4 = G4[(size_t)i4 * 32 + kq]; s.x += t4.x; s.y += t4.y; s.z += t4.z; s.w += t4.w;
    float4 t5 = G4[(size_t)i5 * 32 + kq]; s.x += t5.x; s.y += t5.y; s.z += t5.z; s.w += t5.w;
    float4 bb = B4[kq];
    As[(4 * kq + 0) * 64 + row] = fmaxf(s.x * S6 + bb.x, 0.0f);
    As[(4 * kq + 1) * 64 + row] = fmaxf(s.y * S6 + bb.y, 0.0f);
    As[(4 * kq + 2) * 64 + row] = fmaxf(s.z * S6 + bb.z, 0.0f);
    As[(4 * kq + 3) * 64 + row] = fmaxf(s.w * S6 + bb.w, 0.0f);
  }
  __syncthreads();

  // ---- GEMM: lane = row, wave = 32-col panel, B wave-uniform (SGPR) ----
  int wbase = __builtin_amdgcn_readfirstlane((tid >> 6) << 5);
  wbase &= ~31;  // provable 32-alignment for scalar-load vectorization
  const float* Wb = W + wbase;
  float acc[32];
#pragma unroll
  for (int c = 0; c < 32; c++) acc[c] = 0.0f;
#pragma unroll 2
  for (int k = 0; k < MD; k++) {
    float a = As[k * 64 + row];
    const float* wr = Wb + (size_t)k * MD;
#pragma unroll
    for (int c = 0; c < 32; c++) acc[c] = fmaf(a, wr[c], acc[c]);
  }

  // ---- store C[grow][wbase..wbase+31] ----
  float* Crow = C + (size_t)grow * MD + wbase;
#pragma unroll
  for (int c4 = 0; c4 < 8; c4++) {
    *(float4*)(Crow + 4 * c4) =
        make_float4(acc[4 * c4], acc[4 * c4 + 1], acc[4 * c4 + 2], acc[4 * c4 + 3]);
  }
}

__global__ __launch_bounds__(256) void layer1_kernel(
    const int* __restrict__ z, const int* __restrict__ knn,
    const float* __restrict__ embW, const float* __restrict__ b0,
    const float* __restrict__ W1, float* __restrict__ C) {
  layer_body<0>(z, knn, embW, b0, W1, C);
}

__global__ __launch_bounds__(256) void layer2_kernel(
    const int* __restrict__ knn, const float* __restrict__ h,
    const float* __restrict__ b1, const float* __restrict__ W2,
    float* __restrict__ C) {
  layer_body<1>(nullptr, knn, h, b1, W2, C);
}

// ---------------- tail: agg(layer3) + mean-pool + MLP (validated R2) ----------------
__global__ __launch_bounds__(256) void tail_kernel(
    const float* __restrict__ h3, const int* __restrict__ knn,
    const float* __restrict__ b2, const float* __restrict__ rW1,
    const float* __restrict__ rb1, const float* __restrict__ rW2,
    const float* __restrict__ rb2, const float* __restrict__ rW3,
    const float* __restrict__ rb3, float* __restrict__ out) {
  __shared__ int kl[NPG * KNN];
  __shared__ float part[8 * MD];
  __shared__ float pooled[MD];
  __shared__ float h1s[64];
  __shared__ float h2s[32];
  int g = blockIdx.x;
  int t = threadIdx.x;
  if (t < 250) ((int4*)kl)[t] = ((const int4*)(knn + (size_t)g * NPG * KNN))[t];
  __syncthreads();

  const float4* H = (const float4*)h3;
  int group = t >> 5;
  int cq = t & 31;
  float4 bb = ((const float4*)b2)[cq];
  float4 pool = make_float4(0.f, 0.f, 0.f, 0.f);
  for (int j = 0; j < 25; j++) {
    int n = group * 25 + j;
    size_t gn = (size_t)g * NPG + n;
    const int* kn = kl + n * KNN;
    float4 s = H[gn * 32 + cq];
    int n0 = kn[0], n1 = kn[1], n2 = kn[2], n3 = kn[3], n4 = kn[4];
    float4 t1 = H[(size_t)n0 * 32 + cq]; s.x += t1.x; s.y += t1.y; s.z += t1.z; s.w += t1.w;
    float4 t2 = H[(size_t)n1 * 32 + cq]; s.x += t2.x; s.y += t2.y; s.z += t2.z; s.w += t2.w;
    float4 t3 = H[(size_t)n2 * 32 + cq]; s.x += t3.x; s.y += t3.y; s.z += t3.z; s.w += t3.w;
    float4 t4 = H[(size_t)n3 * 32 + cq]; s.x += t4.x; s.y += t4.y; s.z += t4.z; s.w += t4.w;
    float4 t5 = H[(size_t)n4 * 32 + cq]; s.x += t5.x; s.y += t5.y; s.z += t5.z; s.w += t5.w;
    pool.x += fmaxf(s.x * S6 + bb.x, 0.0f);
    pool.y += fmaxf(s.y * S6 + bb.y, 0.0f);
    pool.z += fmaxf(s.z * S6 + bb.z, 0.0f);
    pool.w += fmaxf(s.w * S6 + bb.w, 0.0f);
  }
  ((float4*)part)[group * 32 + cq] = pool;
  __syncthreads();
  if (t < 32) {
    float4 p = make_float4(0.f, 0.f, 0.f, 0.f);
    for (int gr = 0; gr < 8; gr++) {
      float4 q = ((const float4*)part)[gr * 32 + t];
      p.x += q.x; p.y += q.y; p.z += q.z; p.w += q.w;
    }
    const float inv = 1.0f / (float)NPG;
    p.x *= inv; p.y *= inv; p.z *= inv; p.w *= inv;
    ((float4*)pooled)[t] = p;
  }
  __syncthreads();
  if (t < 64) {
    float a = rb1[t];
    for (int c = 0; c < 128; c++) a += pooled[c] * rW1[c * 64 + t];
    h1s[t] = fmaxf(a, 0.0f);
  }
  __syncthreads();
  if (t < 32) {
    float a = rb2[t];
    for (int c = 0; c < 64; c++) a += h1s[c] * rW2[c * 32 + t];
    h2s[t] = fmaxf(a, 0.0f);
  }
  __syncthreads();
  if (t == 0) {
    float a = rb3[0];
    for (int c = 0; c < 32; c++) a += h2s[c] * rW3[c];
    out[g] = a;
  }
}

extern "C" void kernel_launch(void* const* d_in, const int* in_sizes, int n_in,
                              void* d_out, int out_size, void* d_ws, size_t ws_size,
                              hipStream_t stream) {
  const int* z = (const int*)d_in[0];
  const float* pos = (const float*)d_in[1];
  const float* emb = (const float*)d_in[3];
  const float* convW = (const float*)d_in[4];  // [3][128][128]
  const float* convb = (const float*)d_in[5];  // [3][128]
  const float* rW1 = (const float*)d_in[6];
  const float* rb1 = (const float*)d_in[7];
  const float* rW2 = (const float*)d_in[8];
  const float* rb2 = (const float*)d_in[9];
  const float* rW3 = (const float*)d_in[10];
  const float* rb3 = (const float*)d_in[11];
  float* out = (float*)d_out;

  char* ws = (char*)d_ws;
  int* knn = (int*)ws;                                     // 4,000,000 B
  float* hA = (float*)(ws + 4000000);                      // 102,400,000 B (h2)
  float* hB = (float*)(ws + 4000000 + 102400000ULL);       // 102,400,000 B (h3)
  float* embW = (float*)(ws + 4000000 + 2 * 102400000ULL); // 51,200 B

  knn_kernel<<<NG, 256, 0, stream>>>(pos, knn);
  emb_gemm_kernel<<<50, 256, 0, stream>>>(emb, convW, embW);

  const int grid = NNODES / 64;  // 3125
  // h2 = relu(agg(embW[z]) + b0) @ W1   (layer-1 agg fused into A staging)
  layer1_kernel<<<grid, 256, 0, stream>>>(z, knn, embW, convb,
                                          convW + (size_t)1 * MD * MD, hA);
  // h3 = relu(agg(h2) + b1) @ W2        (layer-2 agg fused into A staging)
  layer2_kernel<<<grid, 256, 0, stream>>>(knn, hA, convb + MD,
                                          convW + (size_t)2 * MD * MD, hB);
  // layer-3 agg + mean-pool + MLP
  tail_kernel<<<NG, 256, 0, stream>>>(hB, knn, convb + 2 * MD, rW1, rb1, rW2,
                                      rb2, rW3, rb3, out);
}

// Round 4
// 334.339 us; speedup vs baseline: 9.9033x; 1.2623x over previous
//
#include <hip/hip_runtime.h>
#include <math.h>

#define NNODES 200000
#define NG 1000
#define NPG 200
#define KNN 5
#define MD 128
#define S6 (1.0f / 6.0f)
#define AP 132  // padded k-stride (words) for LDS tiles

typedef short short8 __attribute__((ext_vector_type(8)));
typedef float floatx4 __attribute__((ext_vector_type(4)));

// RNE bf16 split-pack: returns (bf16(v) << 16) | bf16(v - bf16(v))
__device__ __forceinline__ unsigned splitpack(float f) {
  unsigned u = __float_as_uint(f);
  unsigned hb = (u + 0x7fffu + ((u >> 16) & 1u)) >> 16;
  float hf = __uint_as_float(hb << 16);
  float r = f - hf;
  unsigned v = __float_as_uint(r);
  unsigned lb = (v + 0x7fffu + ((v >> 16) & 1u)) >> 16;
  return (hb << 16) | (lb & 0xffffu);
}

__device__ __forceinline__ void unpack8(int4 u, int4 v, short8* hi, short8* lo) {
  unsigned w[8] = {(unsigned)u.x, (unsigned)u.y, (unsigned)u.z, (unsigned)u.w,
                   (unsigned)v.x, (unsigned)v.y, (unsigned)v.z, (unsigned)v.w};
  short8 h, l;
#pragma unroll
  for (int i = 0; i < 8; i++) {
    h[i] = (short)(w[i] >> 16);
    l[i] = (short)(w[i] & 0xffffu);
  }
  *hi = h;
  *lo = l;
}

// ---------------- kNN: one block per graph (validated R1/R3) ----------------
__global__ __launch_bounds__(256) void knn_kernel(const float* __restrict__ pos,
                                                  int* __restrict__ knn) {
  __shared__ float sp[NPG * 3];
  int g = blockIdx.x;
  int t = threadIdx.x;
  for (int i = t; i < NPG * 3; i += 256) sp[i] = pos[(size_t)g * NPG * 3 + i];
  __syncthreads();
  if (t < NPG) {
    float x = sp[t * 3 + 0], y = sp[t * 3 + 1], z = sp[t * 3 + 2];
    float bd[KNN];
    int bi[KNN];
#pragma unroll
    for (int k = 0; k < KNN; k++) { bd[k] = 3.0e38f; bi[k] = 0; }
    for (int j = 0; j < NPG; j++) {
      if (j == t) continue;
      float dx = __fsub_rn(x, sp[j * 3 + 0]);
      float dy = __fsub_rn(y, sp[j * 3 + 1]);
      float dz = __fsub_rn(z, sp[j * 3 + 2]);
      float d2 = __fadd_rn(__fadd_rn(__fmul_rn(dx, dx), __fmul_rn(dy, dy)),
                           __fmul_rn(dz, dz));
      if (d2 < bd[KNN - 1]) {
        bd[KNN - 1] = d2; bi[KNN - 1] = j;
#pragma unroll
        for (int k = KNN - 1; k > 0; k--) {
          if (bd[k] < bd[k - 1]) {
            float td = bd[k]; bd[k] = bd[k - 1]; bd[k - 1] = td;
            int ti = bi[k]; bi[k] = bi[k - 1]; bi[k - 1] = ti;
          }
        }
      }
    }
#pragma unroll
    for (int k = 0; k < KNN; k++)
      knn[((size_t)g * NPG + t) * KNN + k] = g * NPG + bi[k];
  }
}

// ---------------- embW0 = emb @ W0 (100x128 @ 128x128) ----------------
__global__ __launch_bounds__(256) void emb_gemm_kernel(const float* __restrict__ emb,
                                                       const float* __restrict__ W,
                                                       float* __restrict__ embW) {
  int idx = blockIdx.x * 256 + threadIdx.x;  // 12800 total
  int r = idx >> 7, c = idx & 127;
  float a = 0.0f;
  for (int k = 0; k < MD; k++) a += emb[r * MD + k] * W[k * MD + c];
  embW[idx] = a;
}

// ---------------- fused agg + split-bf16 MFMA GEMM layer ----------------
// Block 256 thr (4 waves). BM=64 rows, BN=128 (two 64-col halves).
// As[64][AP] packed split-pair of post-agg/relu activation (row-major in k).
// Ws[64][AP] packed split-pair of W^T for one 64-col half (n-major rows).
// Wave w -> row-tile rows 16w..16w+15, 4 col-tiles per half.
// x@W = Ahi@Whi + Ahi@Wlo + Alo@Whi via mfma_f32_16x16x32_bf16.
template <int MODE>
__device__ __forceinline__ void layer_body(
    const int* __restrict__ z, const int* __restrict__ knn,
    const float* __restrict__ gsrc,  // MODE 0: embW[100][128]; MODE 1: h[N][128]
    const float* __restrict__ bias,  // this layer's bias (pre-relu) [128]
    const float* __restrict__ W,     // next weight [128][128] k-major
    float* __restrict__ C) {
  __shared__ unsigned As[64 * AP];
  __shared__ unsigned Ws[64 * AP];
  const int tid = threadIdx.x;
  const int row0 = blockIdx.x * 64;

  // ---- stage A: gather-aggregate + bias + relu + split-pack ----
  {
    int r = tid >> 2;       // 0..63
    int kq0 = tid & 3;      // float4-slot base
    int grow = row0 + r;
    const int* kn = knn + (size_t)grow * KNN;
    int i0, i1, i2, i3, i4, i5;
    if (MODE == 0) {
      i0 = z[grow];
      i1 = z[kn[0]]; i2 = z[kn[1]]; i3 = z[kn[2]]; i4 = z[kn[3]]; i5 = z[kn[4]];
    } else {
      i0 = grow;
      i1 = kn[0]; i2 = kn[1]; i3 = kn[2]; i4 = kn[3]; i5 = kn[4];
    }
    const float4* G4 = (const float4*)gsrc;
    const float4* B4 = (const float4*)bias;
#pragma unroll
    for (int p = 0; p < 8; p++) {
      int kq = kq0 + 4 * p;  // 0..31
      float4 s = G4[(size_t)i0 * 32 + kq];
      float4 t1 = G4[(size_t)i1 * 32 + kq]; s.x += t1.x; s.y += t1.y; s.z += t1.z; s.w += t1.w;
      float4 t2 = G4[(size_t)i2 * 32 + kq]; s.x += t2.x; s.y += t2.y; s.z += t2.z; s.w += t2.w;
      float4 t3 = G4[(size_t)i3 * 32 + kq]; s.x += t3.x; s.y += t3.y; s.z += t3.z; s.w += t3.w;
      float4 t4 = G4[(size_t)i4 * 32 + kq]; s.x += t4.x; s.y += t4.y; s.z += t4.z; s.w += t4.w;
      float4 t5 = G4[(size_t)i5 * 32 + kq]; s.x += t5.x; s.y += t5.y; s.z += t5.z; s.w += t5.w;
      float4 bb = B4[kq];
      float a0 = fmaxf(s.x * S6 + bb.x, 0.0f);
      float a1 = fmaxf(s.y * S6 + bb.y, 0.0f);
      float a2 = fmaxf(s.z * S6 + bb.z, 0.0f);
      float a3 = fmaxf(s.w * S6 + bb.w, 0.0f);
      int4 pk = make_int4((int)splitpack(a0), (int)splitpack(a1),
                          (int)splitpack(a2), (int)splitpack(a3));
      *(int4*)(As + r * AP + 4 * kq) = pk;
    }
  }

  const int lane = tid & 63;
  const int wv = tid >> 6;     // wave id 0..3
  const int m = lane & 15;
  const int q = lane >> 4;     // quad 0..3

  // ---- stage W half, transposed+split: Ws[n_local][k] ----
  auto stageW = [&](int n0) {
    int kk = tid >> 4;   // 0..15
    int n4 = tid & 15;   // float4 col group
#pragma unroll
    for (int p = 0; p < 8; p++) {
      int k = kk + 16 * p;
      float4 wvv = *(const float4*)(W + (size_t)k * MD + n0 + 4 * n4);
      Ws[(4 * n4 + 0) * AP + k] = splitpack(wvv.x);
      Ws[(4 * n4 + 1) * AP + k] = splitpack(wvv.y);
      Ws[(4 * n4 + 2) * AP + k] = splitpack(wvv.z);
      Ws[(4 * n4 + 3) * AP + k] = splitpack(wvv.w);
    }
  };

  stageW(0);
  __syncthreads();

  // ---- load A fragments once (reused for both halves) ----
  short8 ahi[4], alo[4];
  {
    const unsigned* ap = As + (16 * wv + m) * AP + 8 * q;
#pragma unroll
    for (int c = 0; c < 4; c++) {
      int4 u = *(const int4*)(ap + 32 * c);
      int4 v = *(const int4*)(ap + 32 * c + 4);
      unpack8(u, v, &ahi[c], &alo[c]);
    }
  }

#pragma unroll
  for (int half = 0; half < 2; half++) {
    if (half == 1) {
      __syncthreads();  // everyone done reading Ws half 0
      stageW(64);
      __syncthreads();
    }
    floatx4 acc[4];
#pragma unroll
    for (int t = 0; t < 4; t++) acc[t] = (floatx4){0.f, 0.f, 0.f, 0.f};
#pragma unroll
    for (int t = 0; t < 4; t++) {
      const unsigned* bp = Ws + (16 * t + m) * AP + 8 * q;
#pragma unroll
      for (int c = 0; c < 4; c++) {
        int4 u = *(const int4*)(bp + 32 * c);
        int4 v = *(const int4*)(bp + 32 * c + 4);
        short8 bhi, blo;
        unpack8(u, v, &bhi, &blo);
        acc[t] = __builtin_amdgcn_mfma_f32_16x16x32_bf16(ahi[c], bhi, acc[t], 0, 0, 0);
        acc[t] = __builtin_amdgcn_mfma_f32_16x16x32_bf16(ahi[c], blo, acc[t], 0, 0, 0);
        acc[t] = __builtin_amdgcn_mfma_f32_16x16x32_bf16(alo[c], bhi, acc[t], 0, 0, 0);
      }
    }
    // store: C/D layout col=lane&15, row=quad*4+reg
#pragma unroll
    for (int t = 0; t < 4; t++) {
      int col = 64 * half + 16 * t + m;
#pragma unroll
      for (int reg = 0; reg < 4; reg++) {
        int row = row0 + 16 * wv + 4 * q + reg;
        C[(size_t)row * MD + col] = acc[t][reg];
      }
    }
  }
}

__global__ __launch_bounds__(256) void layer1_kernel(
    const int* __restrict__ z, const int* __restrict__ knn,
    const float* __restrict__ embW, const float* __restrict__ b0,
    const float* __restrict__ W1, float* __restrict__ C) {
  layer_body<0>(z, knn, embW, b0, W1, C);
}

__global__ __launch_bounds__(256) void layer2_kernel(
    const int* __restrict__ knn, const float* __restrict__ h,
    const float* __restrict__ b1, const float* __restrict__ W2,
    float* __restrict__ C) {
  layer_body<1>(nullptr, knn, h, b1, W2, C);
}

// ---------------- tail: agg(layer3) + mean-pool + MLP (validated R2/R3) ----------------
__global__ __launch_bounds__(256) void tail_kernel(
    const float* __restrict__ h3, const int* __restrict__ knn,
    const float* __restrict__ b2, const float* __restrict__ rW1,
    const float* __restrict__ rb1, const float* __restrict__ rW2,
    const float* __restrict__ rb2, const float* __restrict__ rW3,
    const float* __restrict__ rb3, float* __restrict__ out) {
  __shared__ int kl[NPG * KNN];
  __shared__ float part[8 * MD];
  __shared__ float pooled[MD];
  __shared__ float h1s[64];
  __shared__ float h2s[32];
  int g = blockIdx.x;
  int t = threadIdx.x;
  if (t < 250) ((int4*)kl)[t] = ((const int4*)(knn + (size_t)g * NPG * KNN))[t];
  __syncthreads();

  const float4* H = (const float4*)h3;
  int group = t >> 5;
  int cq = t & 31;
  float4 bb = ((const float4*)b2)[cq];
  float4 pool = make_float4(0.f, 0.f, 0.f, 0.f);
  for (int j = 0; j < 25; j++) {
    int n = group * 25 + j;
    size_t gn = (size_t)g * NPG + n;
    const int* kn = kl + n * KNN;
    float4 s = H[gn * 32 + cq];
    int n0 = kn[0], n1 = kn[1], n2 = kn[2], n3 = kn[3], n4 = kn[4];
    float4 t1 = H[(size_t)n0 * 32 + cq]; s.x += t1.x; s.y += t1.y; s.z += t1.z; s.w += t1.w;
    float4 t2 = H[(size_t)n1 * 32 + cq]; s.x += t2.x; s.y += t2.y; s.z += t2.z; s.w += t2.w;
    float4 t3 = H[(size_t)n2 * 32 + cq]; s.x += t3.x; s.y += t3.y; s.z += t3.z; s.w += t3.w;
    float4 t4 = H[(size_t)n3 * 32 + cq]; s.x += t4.x; s.y += t4.y; s.z += t4.z; s.w += t4.w;
    float4 t5 = H[(size_t)n4 * 32 + cq]; s.x += t5.x; s.y += t5.y; s.z += t5.z; s.w += t5.w;
    pool.x += fmaxf(s.x * S6 + bb.x, 0.0f);
    pool.y += fmaxf(s.y * S6 + bb.y, 0.0f);
    pool.z += fmaxf(s.z * S6 + bb.z, 0.0f);
    pool.w += fmaxf(s.w * S6 + bb.w, 0.0f);
  }
  ((float4*)part)[group * 32 + cq] = pool;
  __syncthreads();
  if (t < 32) {
    float4 p = make_float4(0.f, 0.f, 0.f, 0.f);
    for (int gr = 0; gr < 8; gr++) {
      float4 q = ((const float4*)part)[gr * 32 + t];
      p.x += q.x; p.y += q.y; p.z += q.z; p.w += q.w;
    }
    const float inv = 1.0f / (float)NPG;
    p.x *= inv; p.y *= inv; p.z *= inv; p.w *= inv;
    ((float4*)pooled)[t] = p;
  }
  __syncthreads();
  if (t < 64) {
    float a = rb1[t];
    for (int c = 0; c < 128; c++) a += pooled[c] * rW1[c * 64 + t];
    h1s[t] = fmaxf(a, 0.0f);
  }
  __syncthreads();
  if (t < 32) {
    float a = rb2[t];
    for (int c = 0; c < 64; c++) a += h1s[c] * rW2[c * 32 + t];
    h2s[t] = fmaxf(a, 0.0f);
  }
  __syncthreads();
  if (t == 0) {
    float a = rb3[0];
    for (int c = 0; c < 32; c++) a += h2s[c] * rW3[c];
    out[g] = a;
  }
}

extern "C" void kernel_launch(void* const* d_in, const int* in_sizes, int n_in,
                              void* d_out, int out_size, void* d_ws, size_t ws_size,
                              hipStream_t stream) {
  const int* z = (const int*)d_in[0];
  const float* pos = (const float*)d_in[1];
  const float* emb = (const float*)d_in[3];
  const float* convW = (const float*)d_in[4];  // [3][128][128]
  const float* convb = (const float*)d_in[5];  // [3][128]
  const float* rW1 = (const float*)d_in[6];
  const float* rb1 = (const float*)d_in[7];
  const float* rW2 = (const float*)d_in[8];
  const float* rb2 = (const float*)d_in[9];
  const float* rW3 = (const float*)d_in[10];
  const float* rb3 = (const float*)d_in[11];
  float* out = (float*)d_out;

  char* ws = (char*)d_ws;
  int* knn = (int*)ws;                                     // 4,000,000 B
  float* hA = (float*)(ws + 4000000);                      // 102,400,000 B (h2)
  float* hB = (float*)(ws + 4000000 + 102400000ULL);       // 102,400,000 B (h3)
  float* embW = (float*)(ws + 4000000 + 2 * 102400000ULL); // 51,200 B

  knn_kernel<<<NG, 256, 0, stream>>>(pos, knn);
  emb_gemm_kernel<<<50, 256, 0, stream>>>(emb, convW, embW);

  const int grid = NNODES / 64;  // 3125
  // h2 = relu(agg(embW[z]) + b0) @ W1   (layer-1 agg fused into A staging)
  layer1_kernel<<<grid, 256, 0, stream>>>(z, knn, embW, convb,
                                          convW + (size_t)1 * MD * MD, hA);
  // h3 = relu(agg(h2) + b1) @ W2        (layer-2 agg fused into A staging)
  layer2_kernel<<<grid, 256, 0, stream>>>(knn, hA, convb + MD,
                                          convW + (size_t)2 * MD * MD, hB);
  // layer-3 agg + mean-pool + MLP
  tail_kernel<<<NG, 256, 0, stream>>>(hB, knn, convb + 2 * MD, rW1, rb1, rW2,
                                      rb2, rW3, rb3, out);
}

// Round 5
// 269.546 us; speedup vs baseline: 12.2839x; 1.2404x over previous
//
#include <hip/hip_runtime.h>
#include <math.h>

#define NNODES 200000
#define NG 1000
#define NPG 200
#define KNN 5
#define MD 128
#define S6 (1.0f / 6.0f)

typedef short short8 __attribute__((ext_vector_type(8)));
typedef float floatx4 __attribute__((ext_vector_type(4)));

// RNE bf16 split-pack: returns (bf16(v) << 16) | bf16(v - bf16(v))
__device__ __forceinline__ unsigned splitpack(float f) {
  unsigned u = __float_as_uint(f);
  unsigned hb = (u + 0x7fffu + ((u >> 16) & 1u)) >> 16;
  float hf = __uint_as_float(hb << 16);
  float r = f - hf;
  unsigned v = __float_as_uint(r);
  unsigned lb = (v + 0x7fffu + ((v >> 16) & 1u)) >> 16;
  return (hb << 16) | (lb & 0xffffu);
}

__device__ __forceinline__ void unpack8(int4 u, int4 v, short8* hi, short8* lo) {
  unsigned w[8] = {(unsigned)u.x, (unsigned)u.y, (unsigned)u.z, (unsigned)u.w,
                   (unsigned)v.x, (unsigned)v.y, (unsigned)v.z, (unsigned)v.w};
  short8 h, l;
#pragma unroll
  for (int i = 0; i < 8; i++) {
    h[i] = (short)(w[i] >> 16);
    l[i] = (short)(w[i] & 0xffffu);
  }
  *hi = h;
  *lo = l;
}

// ---------------- kNN: one block per graph (validated R1/R3/R4) ----------------
__global__ __launch_bounds__(256) void knn_kernel(const float* __restrict__ pos,
                                                  int* __restrict__ knn) {
  __shared__ float sp[NPG * 3];
  int g = blockIdx.x;
  int t = threadIdx.x;
  for (int i = t; i < NPG * 3; i += 256) sp[i] = pos[(size_t)g * NPG * 3 + i];
  __syncthreads();
  if (t < NPG) {
    float x = sp[t * 3 + 0], y = sp[t * 3 + 1], z = sp[t * 3 + 2];
    float bd[KNN];
    int bi[KNN];
#pragma unroll
    for (int k = 0; k < KNN; k++) { bd[k] = 3.0e38f; bi[k] = 0; }
    for (int j = 0; j < NPG; j++) {
      if (j == t) continue;
      float dx = __fsub_rn(x, sp[j * 3 + 0]);
      float dy = __fsub_rn(y, sp[j * 3 + 1]);
      float dz = __fsub_rn(z, sp[j * 3 + 2]);
      float d2 = __fadd_rn(__fadd_rn(__fmul_rn(dx, dx), __fmul_rn(dy, dy)),
                           __fmul_rn(dz, dz));
      if (d2 < bd[KNN - 1]) {
        bd[KNN - 1] = d2; bi[KNN - 1] = j;
#pragma unroll
        for (int k = KNN - 1; k > 0; k--) {
          if (bd[k] < bd[k - 1]) {
            float td = bd[k]; bd[k] = bd[k - 1]; bd[k - 1] = td;
            int ti = bi[k]; bi[k] = bi[k - 1]; bi[k - 1] = ti;
          }
        }
      }
    }
#pragma unroll
    for (int k = 0; k < KNN; k++)
      knn[((size_t)g * NPG + t) * KNN + k] = g * NPG + bi[k];
  }
}

// ---------------- embW0 = emb @ W0 (100x128 @ 128x128) ----------------
__global__ __launch_bounds__(256) void emb_gemm_kernel(const float* __restrict__ emb,
                                                       const float* __restrict__ W,
                                                       float* __restrict__ embW) {
  int idx = blockIdx.x * 256 + threadIdx.x;  // 12800 total
  int r = idx >> 7, c = idx & 127;
  float a = 0.0f;
  for (int k = 0; k < MD; k++) a += emb[r * MD + k] * W[k * MD + c];
  embW[idx] = a;
}

// ---------------- pre-pack W1,W2 into MFMA B-fragment layout ----------------
// Layout: [layer(2)][T(8 n-tiles)][c(4 k-chunks)][lane(64)][j(8)] bf16 shorts.
// B frag (verified R4): lane holds B[k = 8*(lane>>4)+j + 32c][n = 16T + (lane&15)].
__global__ __launch_bounds__(256) void prepack_kernel(const float* __restrict__ convW,
                                                      unsigned short* __restrict__ WhiF,
                                                      unsigned short* __restrict__ WloF) {
  int idx = blockIdx.x * 256 + threadIdx.x;  // 0..4095
  int lane = idx & 63;
  int c = (idx >> 6) & 3;
  int T = (idx >> 8) & 7;
  int l = idx >> 11;  // 0..1 -> W1, W2
  const float* W = convW + (size_t)(l + 1) * MD * MD;
  int m = lane & 15, q = lane >> 4;
  int n = 16 * T + m;
  unsigned short hi[8], lo[8];
#pragma unroll
  for (int j = 0; j < 8; j++) {
    int k = 32 * c + 8 * q + j;
    unsigned p = splitpack(W[(size_t)k * MD + n]);
    hi[j] = (unsigned short)(p >> 16);
    lo[j] = (unsigned short)(p & 0xffffu);
  }
  *(short8*)(WhiF + (size_t)idx * 8) = *(short8*)hi;
  *(short8*)(WloF + (size_t)idx * 8) = *(short8*)lo;
}

// ---------------- fused agg + split-bf16 MFMA GEMM layer ----------------
// Block 256 thr (4 waves). BM=64 rows, BN=128. Wave wv: rh=wv&1 (row half,
// 32 rows), hf=wv>>1 (col half, 64 cols) -> each wave reads only 32 KB of W frags.
// As[64][128] packed (hi|lo) words, XOR-swizzled by (row&7) on 4-word granules:
// conflict-free writes and b128 frag reads. B frags load straight from global
// (prepacked, coalesced 16B/lane, L2-resident). x@W = Ahi@Whi+Ahi@Wlo+Alo@Whi.
template <int MODE>
__device__ __forceinline__ void layer_body(
    const int* __restrict__ z, const int* __restrict__ knn,
    const float* __restrict__ gsrc,  // MODE 0: embW[100][128]; MODE 1: h[N][128]
    const float* __restrict__ bias,  // this layer's bias (pre-relu) [128]
    const unsigned short* __restrict__ WhiF,
    const unsigned short* __restrict__ WloF,
    float* __restrict__ C) {
  __shared__ unsigned As[64 * 128];  // 32 KB
  const int tid = threadIdx.x;

  // XCD-aware remap: 4 consecutive logical blocks per XCD (L2 graph locality).
  int b = blockIdx.x;
  int lb;
  if (b < 3072) {
    int grp = b >> 5, r8 = b & 7, r4 = (b >> 3) & 3;
    lb = grp * 32 + r8 * 4 + r4;
  } else {
    lb = b;
  }
  const int row0 = lb * 64;

  // ---- stage A: gather-aggregate + bias + relu + split-pack, swizzled ----
  {
    int r = tid >> 2;   // 0..63
    int kq0 = tid & 3;  // granule base
    int grow = row0 + r;
    const int* kn = knn + (size_t)grow * KNN;
    int i0, i1, i2, i3, i4, i5;
    if (MODE == 0) {
      i0 = z[grow];
      i1 = z[kn[0]]; i2 = z[kn[1]]; i3 = z[kn[2]]; i4 = z[kn[3]]; i5 = z[kn[4]];
    } else {
      i0 = grow;
      i1 = kn[0]; i2 = kn[1]; i3 = kn[2]; i4 = kn[3]; i5 = kn[4];
    }
    const float4* G4 = (const float4*)gsrc;
    const float4* B4 = (const float4*)bias;
    int sw = r & 7;
#pragma unroll
    for (int p = 0; p < 8; p++) {
      int kq = kq0 + 4 * p;  // granule 0..31
      float4 s = G4[(size_t)i0 * 32 + kq];
      float4 t1 = G4[(size_t)i1 * 32 + kq]; s.x += t1.x; s.y += t1.y; s.z += t1.z; s.w += t1.w;
      float4 t2 = G4[(size_t)i2 * 32 + kq]; s.x += t2.x; s.y += t2.y; s.z += t2.z; s.w += t2.w;
      float4 t3 = G4[(size_t)i3 * 32 + kq]; s.x += t3.x; s.y += t3.y; s.z += t3.z; s.w += t3.w;
      float4 t4 = G4[(size_t)i4 * 32 + kq]; s.x += t4.x; s.y += t4.y; s.z += t4.z; s.w += t4.w;
      float4 t5 = G4[(size_t)i5 * 32 + kq]; s.x += t5.x; s.y += t5.y; s.z += t5.z; s.w += t5.w;
      float4 bb = B4[kq];
      int4 pk;
      pk.x = (int)splitpack(fmaxf(s.x * S6 + bb.x, 0.0f));
      pk.y = (int)splitpack(fmaxf(s.y * S6 + bb.y, 0.0f));
      pk.z = (int)splitpack(fmaxf(s.z * S6 + bb.z, 0.0f));
      pk.w = (int)splitpack(fmaxf(s.w * S6 + bb.w, 0.0f));
      *(int4*)(As + r * 128 + ((kq ^ sw) << 2)) = pk;
    }
  }
  __syncthreads();

  const int lane = tid & 63;
  const int wv = tid >> 6;
  const int m = lane & 15;
  const int q = lane >> 4;
  const int rh = wv & 1;   // row half: rows 32*rh..
  const int hf = wv >> 1;  // col half: cols 64*hf..

  // ---- A fragments: 2 row-tiles x 4 k-chunks ----
  short8 ahi[2][4], alo[2][4];
#pragma unroll
  for (int rt = 0; rt < 2; rt++) {
    int r = 32 * rh + 16 * rt + m;
    const unsigned* base = As + r * 128;
    int sw = m & 7;  // r&7 == m&7 (32rh+16rt multiple of 8... 16rt: 16%8=0 ok)
#pragma unroll
    for (int c = 0; c < 4; c++) {
      int g1 = (2 * q + 8 * c) ^ sw;
      int g2 = (2 * q + 8 * c + 1) ^ sw;
      int4 u = *(const int4*)(base + (g1 << 2));
      int4 v = *(const int4*)(base + (g2 << 2));
      unpack8(u, v, &ahi[rt][c], &alo[rt][c]);
    }
  }

  // ---- MFMA: 4 col-tiles (within this wave's col half) x 2 row-tiles ----
#pragma unroll
  for (int t = 0; t < 4; t++) {
    floatx4 acc[2];
    acc[0] = (floatx4){0.f, 0.f, 0.f, 0.f};
    acc[1] = (floatx4){0.f, 0.f, 0.f, 0.f};
    int T = hf * 4 + t;
#pragma unroll
    for (int c = 0; c < 4; c++) {
      size_t off = ((size_t)(T * 4 + c) * 64 + lane) * 8;
      short8 bhi = *(const short8*)(WhiF + off);
      short8 blo = *(const short8*)(WloF + off);
#pragma unroll
      for (int rt = 0; rt < 2; rt++) {
        acc[rt] = __builtin_amdgcn_mfma_f32_16x16x32_bf16(ahi[rt][c], bhi, acc[rt], 0, 0, 0);
        acc[rt] = __builtin_amdgcn_mfma_f32_16x16x32_bf16(ahi[rt][c], blo, acc[rt], 0, 0, 0);
        acc[rt] = __builtin_amdgcn_mfma_f32_16x16x32_bf16(alo[rt][c], bhi, acc[rt], 0, 0, 0);
      }
    }
    int col = 64 * hf + 16 * t + m;  // C/D: col = lane&15 (+tile), row = 4q+reg
#pragma unroll
    for (int rt = 0; rt < 2; rt++) {
#pragma unroll
      for (int reg = 0; reg < 4; reg++) {
        int row = row0 + 32 * rh + 16 * rt + 4 * q + reg;
        C[(size_t)row * MD + col] = acc[rt][reg];
      }
    }
  }
}

__global__ __launch_bounds__(256) void layer1_kernel(
    const int* __restrict__ z, const int* __restrict__ knn,
    const float* __restrict__ embW, const float* __restrict__ b0,
    const unsigned short* __restrict__ WhiF, const unsigned short* __restrict__ WloF,
    float* __restrict__ C) {
  layer_body<0>(z, knn, embW, b0, WhiF, WloF, C);
}

__global__ __launch_bounds__(256) void layer2_kernel(
    const int* __restrict__ knn, const float* __restrict__ h,
    const float* __restrict__ b1,
    const unsigned short* __restrict__ WhiF, const unsigned short* __restrict__ WloF,
    float* __restrict__ C) {
  layer_body<1>(nullptr, knn, h, b1, WhiF, WloF, C);
}

// ---------------- tail: agg(layer3) + mean-pool + MLP, 512 thr/graph ----------------
__global__ __launch_bounds__(512) void tail_kernel(
    const float* __restrict__ h3, const int* __restrict__ knn,
    const float* __restrict__ b2, const float* __restrict__ rW1,
    const float* __restrict__ rb1, const float* __restrict__ rW2,
    const float* __restrict__ rb2, const float* __restrict__ rW3,
    const float* __restrict__ rb3, float* __restrict__ out) {
  __shared__ int kl[NPG * KNN];
  __shared__ float part[16 * MD];
  __shared__ float pooled[MD];
  __shared__ float h1s[64];
  __shared__ float h2s[32];
  int g = blockIdx.x;
  int t = threadIdx.x;
  if (t < 250) ((int4*)kl)[t] = ((const int4*)(knn + (size_t)g * NPG * KNN))[t];
  __syncthreads();

  const float4* H = (const float4*)h3;
  int group = t >> 5;  // 0..15
  int cq = t & 31;     // float4 column index
  float4 bb = ((const float4*)b2)[cq];
  float4 pool = make_float4(0.f, 0.f, 0.f, 0.f);
  for (int j = 0;; j++) {
    int n = group + 16 * j;
    if (n >= NPG) break;
    size_t gn = (size_t)g * NPG + n;
    const int* kn = kl + n * KNN;
    float4 s = H[gn * 32 + cq];
    int n0 = kn[0], n1 = kn[1], n2 = kn[2], n3 = kn[3], n4 = kn[4];
    float4 t1 = H[(size_t)n0 * 32 + cq]; s.x += t1.x; s.y += t1.y; s.z += t1.z; s.w += t1.w;
    float4 t2 = H[(size_t)n1 * 32 + cq]; s.x += t2.x; s.y += t2.y; s.z += t2.z; s.w += t2.w;
    float4 t3 = H[(size_t)n2 * 32 + cq]; s.x += t3.x; s.y += t3.y; s.z += t3.z; s.w += t3.w;
    float4 t4 = H[(size_t)n3 * 32 + cq]; s.x += t4.x; s.y += t4.y; s.z += t4.z; s.w += t4.w;
    float4 t5 = H[(size_t)n4 * 32 + cq]; s.x += t5.x; s.y += t5.y; s.z += t5.z; s.w += t5.w;
    pool.x += fmaxf(s.x * S6 + bb.x, 0.0f);
    pool.y += fmaxf(s.y * S6 + bb.y, 0.0f);
    pool.z += fmaxf(s.z * S6 + bb.z, 0.0f);
    pool.w += fmaxf(s.w * S6 + bb.w, 0.0f);
  }
  ((float4*)part)[group * 32 + cq] = pool;
  __syncthreads();
  if (t < 32) {
    float4 p = make_float4(0.f, 0.f, 0.f, 0.f);
    for (int gr = 0; gr < 16; gr++) {
      float4 qv = ((const float4*)part)[gr * 32 + t];
      p.x += qv.x; p.y += qv.y; p.z += qv.z; p.w += qv.w;
    }
    const float inv = 1.0f / (float)NPG;
    p.x *= inv; p.y *= inv; p.z *= inv; p.w *= inv;
    ((float4*)pooled)[t] = p;
  }
  __syncthreads();
  if (t < 64) {
    float a = rb1[t];
    for (int c = 0; c < 128; c++) a += pooled[c] * rW1[c * 64 + t];
    h1s[t] = fmaxf(a, 0.0f);
  }
  __syncthreads();
  if (t < 32) {
    float a = rb2[t];
    for (int c = 0; c < 64; c++) a += h1s[c] * rW2[c * 32 + t];
    h2s[t] = fmaxf(a, 0.0f);
  }
  __syncthreads();
  if (t == 0) {
    float a = rb3[0];
    for (int c = 0; c < 32; c++) a += h2s[c] * rW3[c];
    out[g] = a;
  }
}

extern "C" void kernel_launch(void* const* d_in, const int* in_sizes, int n_in,
                              void* d_out, int out_size, void* d_ws, size_t ws_size,
                              hipStream_t stream) {
  const int* z = (const int*)d_in[0];
  const float* pos = (const float*)d_in[1];
  const float* emb = (const float*)d_in[3];
  const float* convW = (const float*)d_in[4];  // [3][128][128]
  const float* convb = (const float*)d_in[5];  // [3][128]
  const float* rW1 = (const float*)d_in[6];
  const float* rb1 = (const float*)d_in[7];
  const float* rW2 = (const float*)d_in[8];
  const float* rb2 = (const float*)d_in[9];
  const float* rW3 = (const float*)d_in[10];
  const float* rb3 = (const float*)d_in[11];
  float* out = (float*)d_out;

  char* ws = (char*)d_ws;
  int* knn = (int*)ws;                                        // 4,000,000 B
  float* hA = (float*)(ws + 4000000);                         // 102,400,000 B (h2)
  float* hB = (float*)(ws + 4000000 + 102400000ULL);          // 102,400,000 B (h3)
  float* embW = (float*)(ws + 4000000 + 2 * 102400000ULL);    // 51,200 B
  unsigned short* WhiF = (unsigned short*)(ws + 4000000 + 2 * 102400000ULL + 51200);  // 65,536 B
  unsigned short* WloF = WhiF + 32768;                        // 65,536 B

  knn_kernel<<<NG, 256, 0, stream>>>(pos, knn);
  emb_gemm_kernel<<<50, 256, 0, stream>>>(emb, convW, embW);
  prepack_kernel<<<16, 256, 0, stream>>>(convW, WhiF, WloF);

  const int grid = NNODES / 64;  // 3125
  // h2 = relu(agg(embW[z]) + b0) @ W1
  layer1_kernel<<<grid, 256, 0, stream>>>(z, knn, embW, convb, WhiF, WloF, hA);
  // h3 = relu(agg(h2) + b1) @ W2
  layer2_kernel<<<grid, 256, 0, stream>>>(knn, hA, convb + MD, WhiF + 16384,
                                          WloF + 16384, hB);
  // layer-3 agg + mean-pool + MLP
  tail_kernel<<<NG, 512, 0, stream>>>(hB, knn, convb + 2 * MD, rW1, rb1, rW2,
                                      rb2, rW3, rb3, out);
}